// Round 4
// baseline (59.349 us; speedup 1.0000x reference)
//
#include <hip/hip_runtime.h>

// Segment-mean over N rows of F=256 f32 features into C=37 classes,
// scattered into queue[C][2][F] at slot tail[c].
//
// k_accum: one row per WAVE via float4 (lane l owns cols [4l,4l+4)), each
// wave has a PRIVATE 37KB LDS class-sum buffer -> no cross-wave races, no
// atomics. Software-pipelined: first prefetch is issued BEFORE the LDS zero
// loop so HBM starts immediately; next 8 rows load while current 8 RMW.
// Feature loads are nontemporal (stream-once data, keep L2 for partials).

constexpr int C   = 37;
constexpr int F   = 256;
constexpr int WPB = 4;    // waves per block

typedef float f4v __attribute__((ext_vector_type(4)));

__global__ __launch_bounds__(256) void k_accum(
    const float* __restrict__ feat, const int* __restrict__ labels,
    float* __restrict__ psums, float* __restrict__ pcnts, int rpw)
{
    __shared__ float ls[WPB][C * F];     // 4 x 37888 B = 148 KB
    __shared__ int   lcnt[WPB][64];
    const int t = threadIdx.x;
    const int w = t >> 6;
    const int l = t & 63;

    const size_t rbase = (size_t)blockIdx.x * (size_t)(rpw * WPB) + (size_t)w * rpw;
    const f4v* f4 = (const f4v*)feat;      // row r -> f4[r*64 + l]

    // Issue the first prefetch BEFORE zeroing LDS: HBM starts now, the zero
    // loop (~200 cy of LDS writes) runs under the load latency.
    f4v buf[8]; int cls[8];
    #pragma unroll
    for (int k = 0; k < 8; ++k) {
        buf[k] = __builtin_nontemporal_load(&f4[(rbase + k) * 64 + l]);
        cls[k] = labels[rbase + k];
    }

    // Each wave zeroes its own buffer (no cross-wave sync needed).
    f4v* lz = (f4v*)ls[w];
    for (int i = l; i < C * F / 4; i += 64)
        lz[i] = (f4v)(0.f);

    int cnt = 0;   // count for class l (meaningful for l < C)

    for (int i = 0; i < rpw; i += 8) {
        f4v nbuf[8]; int ncls[8];
        const bool more = (i + 8) < rpw;     // wave-uniform branch
        if (more) {
            #pragma unroll
            for (int k = 0; k < 8; ++k) {
                nbuf[k] = __builtin_nontemporal_load(&f4[(rbase + i + 8 + k) * 64 + l]);
                ncls[k] = labels[rbase + i + 8 + k];
            }
        }
        #pragma unroll
        for (int k = 0; k < 8; ++k) {
            const int c = cls[k];
            cnt += (c == l);
            f4v* p = (f4v*)&ls[w][c * F + 4 * l];  // lane-exclusive 16B slot
            *p = *p + buf[k];
        }
        if (more) {
            #pragma unroll
            for (int k = 0; k < 8; ++k) { buf[k] = nbuf[k]; cls[k] = ncls[k]; }
        }
    }

    lcnt[w][l] = cnt;
    __syncthreads();

    // Reduce the 4 wave buffers, write this block's partials (vectorized).
    f4v* po = (f4v*)(psums + (size_t)blockIdx.x * (C * F));
    const f4v* b0 = (const f4v*)ls[0];
    const f4v* b1 = (const f4v*)ls[1];
    const f4v* b2 = (const f4v*)ls[2];
    const f4v* b3 = (const f4v*)ls[3];
    for (int i = t; i < C * F / 4; i += 256)
        po[i] = (b0[i] + b1[i]) + (b2[i] + b3[i]);
    if (t < C)
        pcnts[(size_t)blockIdx.x * C + t] =
            (float)(lcnt[0][t] + lcnt[1][t] + lcnt[2][t] + lcnt[3][t]);
}

__global__ __launch_bounds__(256) void k_reduce(
    const float* __restrict__ psums, float* __restrict__ s2, int per_stripe)
{
    const int c = blockIdx.x;        // class
    const int s = blockIdx.y;        // stripe
    const int t = threadIdx.x;       // column
    const int b0 = s * per_stripe;
    float acc = 0.f;
    #pragma unroll 8
    for (int b = b0; b < b0 + per_stripe; ++b)
        acc += psums[((size_t)b * C + c) * F + t];
    s2[((size_t)s * C + c) * F + t] = acc;
}

__global__ __launch_bounds__(256) void k_final(
    const float* __restrict__ s2, const float* __restrict__ pcnts,
    const float* __restrict__ queue, const int* __restrict__ tail,
    float* __restrict__ out, int NB, int S)
{
    const int c = blockIdx.x;
    const int t = threadIdx.x;

    float s = 0.f;
    for (int k = 0; k < S; ++k) s += s2[((size_t)k * C + c) * F + t];

    __shared__ float red[256];
    float cnt = 0.f;
    for (int b = t; b < NB; b += 256) cnt += pcnts[(size_t)b * C + c];
    red[t] = cnt;
    __syncthreads();
    for (int off = 128; off > 0; off >>= 1) {
        if (t < off) red[t] += red[t + off];
        __syncthreads();
    }
    const float total = red[0];

    int tl = tail[c];
    tl = tl < 0 ? 0 : (tl > 1 ? 1 : tl);
    const bool  present = total > 0.f;
    const float mean    = s / fmaxf(total, 1.f);

    const float q0 = queue[((size_t)c * 2 + 0) * F + t];
    const float q1 = queue[((size_t)c * 2 + 1) * F + t];
    float o0 = q0, o1 = q1;
    if (tl == 0) o0 = present ? mean : q0;
    else         o1 = present ? mean : q1;
    out[((size_t)c * 2 + 0) * F + t] = o0;
    out[((size_t)c * 2 + 1) * F + t] = o1;
}

extern "C" void kernel_launch(void* const* d_in, const int* in_sizes, int n_in,
                              void* d_out, int out_size, void* d_ws, size_t ws_size,
                              hipStream_t stream)
{
    const float* feat   = (const float*)d_in[0];
    const int*   labels = (const int*)d_in[1];
    const float* queue  = (const float*)d_in[2];
    const int*   tail   = (const int*)d_in[3];
    float* out = (float*)d_out;
    float* ws  = (float*)d_ws;

    const int N = in_sizes[1];   // number of rows
    const int S = 8;

    // NB = number of accum blocks (power of two), sized to fit workspace.
    int NB = 256;
    while (NB > 32) {
        size_t need = ((size_t)NB * C * F + (size_t)NB * C + (size_t)S * C * F + 64) * sizeof(float);
        if (need <= ws_size) break;
        NB >>= 1;
    }
    const int rpw = N / (NB * WPB);   // rows per wave

    float* psums = ws;
    float* pcnts = psums + (size_t)NB * C * F;
    float* s2    = pcnts + (size_t)NB * C;

    hipLaunchKernelGGL(k_accum,  dim3(NB),   dim3(256), 0, stream,
                       feat, labels, psums, pcnts, rpw);
    hipLaunchKernelGGL(k_reduce, dim3(C, S), dim3(256), 0, stream,
                       psums, s2, NB / S);
    hipLaunchKernelGGL(k_final,  dim3(C),    dim3(256), 0, stream,
                       s2, pcnts, queue, tail, out, NB, S);
}

// Round 5
// 59.254 us; speedup vs baseline: 1.0016x; 1.0016x over previous
//
#include <hip/hip_runtime.h>

// Segment-mean over N rows of F=256 f32 features into C=37 classes,
// scattered into queue[C][2][F] at slot tail[c].
//
// k_accum: one row per WAVE via float4 (lane l owns cols [4l,4l+4)), each
// wave has a PRIVATE 37KB LDS class-sum buffer -> no cross-wave races, no
// atomics. Software-pipelined: first prefetch is issued BEFORE the LDS zero
// loop so HBM starts immediately; next 8 rows load while current 8 RMW.
// Feature loads are nontemporal (stream-once data, keep L2 for partials).

constexpr int C   = 37;
constexpr int F   = 256;
constexpr int WPB = 4;    // waves per block

typedef float f4v __attribute__((ext_vector_type(4)));

__global__ __launch_bounds__(256) void k_accum(
    const float* __restrict__ feat, const int* __restrict__ labels,
    float* __restrict__ psums, float* __restrict__ pcnts, int rpw)
{
    __shared__ float ls[WPB][C * F];     // 4 x 37888 B = 148 KB
    __shared__ int   lcnt[WPB][64];
    const int t = threadIdx.x;
    const int w = t >> 6;
    const int l = t & 63;

    const size_t rbase = (size_t)blockIdx.x * (size_t)(rpw * WPB) + (size_t)w * rpw;
    const f4v* f4 = (const f4v*)feat;      // row r -> f4[r*64 + l]

    // Issue the first prefetch BEFORE zeroing LDS: HBM starts now, the zero
    // loop (~200 cy of LDS writes) runs under the load latency.
    f4v buf[8]; int cls[8];
    #pragma unroll
    for (int k = 0; k < 8; ++k) {
        buf[k] = __builtin_nontemporal_load(&f4[(rbase + k) * 64 + l]);
        cls[k] = labels[rbase + k];
    }

    // Each wave zeroes its own buffer (no cross-wave sync needed).
    f4v* lz = (f4v*)ls[w];
    for (int i = l; i < C * F / 4; i += 64)
        lz[i] = (f4v)(0.f);

    int cnt = 0;   // count for class l (meaningful for l < C)

    for (int i = 0; i < rpw; i += 8) {
        f4v nbuf[8]; int ncls[8];
        const bool more = (i + 8) < rpw;     // wave-uniform branch
        if (more) {
            #pragma unroll
            for (int k = 0; k < 8; ++k) {
                nbuf[k] = __builtin_nontemporal_load(&f4[(rbase + i + 8 + k) * 64 + l]);
                ncls[k] = labels[rbase + i + 8 + k];
            }
        }
        #pragma unroll
        for (int k = 0; k < 8; ++k) {
            const int c = cls[k];
            cnt += (c == l);
            f4v* p = (f4v*)&ls[w][c * F + 4 * l];  // lane-exclusive 16B slot
            *p = *p + buf[k];
        }
        if (more) {
            #pragma unroll
            for (int k = 0; k < 8; ++k) { buf[k] = nbuf[k]; cls[k] = ncls[k]; }
        }
    }

    lcnt[w][l] = cnt;
    __syncthreads();

    // Reduce the 4 wave buffers, write this block's partials (vectorized).
    f4v* po = (f4v*)(psums + (size_t)blockIdx.x * (C * F));
    const f4v* b0 = (const f4v*)ls[0];
    const f4v* b1 = (const f4v*)ls[1];
    const f4v* b2 = (const f4v*)ls[2];
    const f4v* b3 = (const f4v*)ls[3];
    for (int i = t; i < C * F / 4; i += 256)
        po[i] = (b0[i] + b1[i]) + (b2[i] + b3[i]);
    if (t < C)
        pcnts[(size_t)blockIdx.x * C + t] =
            (float)(lcnt[0][t] + lcnt[1][t] + lcnt[2][t] + lcnt[3][t]);
}

__global__ __launch_bounds__(256) void k_reduce(
    const float* __restrict__ psums, float* __restrict__ s2, int per_stripe)
{
    const int c = blockIdx.x;        // class
    const int s = blockIdx.y;        // stripe
    const int t = threadIdx.x;       // column
    const int b0 = s * per_stripe;
    float acc = 0.f;
    #pragma unroll 8
    for (int b = b0; b < b0 + per_stripe; ++b)
        acc += psums[((size_t)b * C + c) * F + t];
    s2[((size_t)s * C + c) * F + t] = acc;
}

__global__ __launch_bounds__(256) void k_final(
    const float* __restrict__ s2, const float* __restrict__ pcnts,
    const float* __restrict__ queue, const int* __restrict__ tail,
    float* __restrict__ out, int NB, int S)
{
    const int c = blockIdx.x;
    const int t = threadIdx.x;

    float s = 0.f;
    for (int k = 0; k < S; ++k) s += s2[((size_t)k * C + c) * F + t];

    __shared__ float red[256];
    float cnt = 0.f;
    for (int b = t; b < NB; b += 256) cnt += pcnts[(size_t)b * C + c];
    red[t] = cnt;
    __syncthreads();
    for (int off = 128; off > 0; off >>= 1) {
        if (t < off) red[t] += red[t + off];
        __syncthreads();
    }
    const float total = red[0];

    int tl = tail[c];
    tl = tl < 0 ? 0 : (tl > 1 ? 1 : tl);
    const bool  present = total > 0.f;
    const float mean    = s / fmaxf(total, 1.f);

    const float q0 = queue[((size_t)c * 2 + 0) * F + t];
    const float q1 = queue[((size_t)c * 2 + 1) * F + t];
    float o0 = q0, o1 = q1;
    if (tl == 0) o0 = present ? mean : q0;
    else         o1 = present ? mean : q1;
    out[((size_t)c * 2 + 0) * F + t] = o0;
    out[((size_t)c * 2 + 1) * F + t] = o1;
}

extern "C" void kernel_launch(void* const* d_in, const int* in_sizes, int n_in,
                              void* d_out, int out_size, void* d_ws, size_t ws_size,
                              hipStream_t stream)
{
    const float* feat   = (const float*)d_in[0];
    const int*   labels = (const int*)d_in[1];
    const float* queue  = (const float*)d_in[2];
    const int*   tail   = (const int*)d_in[3];
    float* out = (float*)d_out;
    float* ws  = (float*)d_ws;

    const int N = in_sizes[1];   // number of rows
    const int S = 8;

    // NB = number of accum blocks (power of two), sized to fit workspace.
    int NB = 256;
    while (NB > 32) {
        size_t need = ((size_t)NB * C * F + (size_t)NB * C + (size_t)S * C * F + 64) * sizeof(float);
        if (need <= ws_size) break;
        NB >>= 1;
    }
    const int rpw = N / (NB * WPB);   // rows per wave

    float* psums = ws;
    float* pcnts = psums + (size_t)NB * C * F;
    float* s2    = pcnts + (size_t)NB * C;

    hipLaunchKernelGGL(k_accum,  dim3(NB),   dim3(256), 0, stream,
                       feat, labels, psums, pcnts, rpw);
    hipLaunchKernelGGL(k_reduce, dim3(C, S), dim3(256), 0, stream,
                       psums, s2, NB / S);
    hipLaunchKernelGGL(k_final,  dim3(C),    dim3(256), 0, stream,
                       s2, pcnts, queue, tail, out, NB, S);
}

// Round 6
// 54.689 us; speedup vs baseline: 1.0852x; 1.0835x over previous
//
#include <hip/hip_runtime.h>

// Segment-mean over N rows of F=256 f32 features into C=37 classes,
// scattered into queue[C][2][F] at slot tail[c].
//
// k_accum: one row per WAVE via float4 (lane l owns cols [4l,4l+4)), each
// wave has a PRIVATE 37KB LDS class-sum buffer -> no cross-wave races, no
// atomics. (Exact R3 configuration — nontemporal loads regressed, reverted.)
//
// k_tail : merged reduce+finalize. Grid (C,4): block (c,q) reduces all NB
// partials for 64 columns (coalesced, 8-way ILP), tree-reduces b-slices and
// counts in LDS, computes mean, scatters into the queue slot.

constexpr int C   = 37;
constexpr int F   = 256;
constexpr int WPB = 4;    // waves per block

__global__ __launch_bounds__(256) void k_accum(
    const float* __restrict__ feat, const int* __restrict__ labels,
    float* __restrict__ psums, float* __restrict__ pcnts, int rpw)
{
    __shared__ float ls[WPB][C * F];     // 4 x 37888 B = 148 KB
    __shared__ int   lcnt[WPB][64];
    const int t = threadIdx.x;
    const int w = t >> 6;
    const int l = t & 63;

    // Each wave zeroes its own buffer (no sync needed before use).
    float4* lz = (float4*)ls[w];
    for (int i = l; i < C * F / 4; i += 64)
        lz[i] = make_float4(0.f, 0.f, 0.f, 0.f);

    const size_t rbase = (size_t)blockIdx.x * (size_t)(rpw * WPB) + (size_t)w * rpw;
    const float4* f4 = (const float4*)feat;      // row r -> f4[r*64 + l]

    int cnt = 0;   // count for class l (meaningful for l < C)

    float4 buf[8]; int cls[8];
    #pragma unroll
    for (int k = 0; k < 8; ++k) {
        buf[k] = f4[(rbase + k) * 64 + l];
        cls[k] = labels[rbase + k];
    }

    for (int i = 0; i < rpw; i += 8) {
        float4 nbuf[8]; int ncls[8];
        const bool more = (i + 8) < rpw;     // wave-uniform branch
        if (more) {
            #pragma unroll
            for (int k = 0; k < 8; ++k) {
                nbuf[k] = f4[(rbase + i + 8 + k) * 64 + l];
                ncls[k] = labels[rbase + i + 8 + k];
            }
        }
        #pragma unroll
        for (int k = 0; k < 8; ++k) {
            const int c = cls[k];
            cnt += (c == l);
            float4* p = (float4*)&ls[w][c * F + 4 * l];  // lane-exclusive slot
            float4 a = *p;
            a.x += buf[k].x; a.y += buf[k].y; a.z += buf[k].z; a.w += buf[k].w;
            *p = a;
        }
        if (more) {
            #pragma unroll
            for (int k = 0; k < 8; ++k) { buf[k] = nbuf[k]; cls[k] = ncls[k]; }
        }
    }

    lcnt[w][l] = cnt;
    __syncthreads();

    float* po = psums + (size_t)blockIdx.x * (C * F);
    for (int i = t; i < C * F; i += 256)
        po[i] = ls[0][i] + ls[1][i] + ls[2][i] + ls[3][i];
    if (t < C)
        pcnts[(size_t)blockIdx.x * C + t] =
            (float)(lcnt[0][t] + lcnt[1][t] + lcnt[2][t] + lcnt[3][t]);
}

__global__ __launch_bounds__(256) void k_tail(
    const float* __restrict__ psums, const float* __restrict__ pcnts,
    const float* __restrict__ queue, const int* __restrict__ tail,
    float* __restrict__ out, int NB)
{
    const int c  = blockIdx.x;          // class
    const int q  = blockIdx.y;          // column quarter (0..3)
    const int t  = threadIdx.x;
    const int cl = t & 63;              // column within quarter
    const int bs = t >> 6;              // b-slice (0..3)
    const int col = q * 64 + cl;
    const int npb = NB >> 2;            // partials per slice

    // 8-way unrolled partial-sum reduction: coalesced 256B per load instr.
    float a0 = 0.f, a1 = 0.f, a2 = 0.f, a3 = 0.f;
    float a4 = 0.f, a5 = 0.f, a6 = 0.f, a7 = 0.f;
    const size_t stride = (size_t)C * F;
    const float* p = psums + (size_t)(bs * npb) * stride + (size_t)c * F + col;
    for (int b = 0; b < npb; b += 8) {
        a0 += p[(size_t)(b + 0) * stride];
        a1 += p[(size_t)(b + 1) * stride];
        a2 += p[(size_t)(b + 2) * stride];
        a3 += p[(size_t)(b + 3) * stride];
        a4 += p[(size_t)(b + 4) * stride];
        a5 += p[(size_t)(b + 5) * stride];
        a6 += p[(size_t)(b + 6) * stride];
        a7 += p[(size_t)(b + 7) * stride];
    }
    const float acc = ((a0 + a1) + (a2 + a3)) + ((a4 + a5) + (a6 + a7));

    __shared__ float reds[256];
    __shared__ float redc[256];
    reds[t] = acc;
    // counts: NB values, each thread grabs its share (tiny, L2-resident)
    float cnt = 0.f;
    for (int b = t; b < NB; b += 256) cnt += pcnts[(size_t)b * C + c];
    redc[t] = cnt;
    __syncthreads();

    if (t < 64) {
        const float s = ((reds[t] + reds[t + 64]) + (reds[t + 128] + reds[t + 192]));
        // full count tree: 256 -> 1 (done redundantly per lane via LDS reads)
        float total = 0.f;
        #pragma unroll
        for (int k = 0; k < 4; ++k) total += redc[t + 64 * k];
        // reduce across the 64 lanes' partial counts via shuffle
        float tot = redc[0];  // placeholder; recompute properly below
        (void)tot;
        // lane-local partials -> wave reduce
        float ctot = total;
        #pragma unroll
        for (int off = 32; off > 0; off >>= 1)
            ctot += __shfl_down(ctot, off, 64);
        ctot = __shfl(ctot, 0, 64);

        const bool  present = ctot > 0.f;
        const float mean    = s / fmaxf(ctot, 1.f);

        int tl = tail[c];
        tl = tl < 0 ? 0 : (tl > 1 ? 1 : tl);

        const float q0 = queue[((size_t)c * 2 + 0) * F + col];
        const float q1 = queue[((size_t)c * 2 + 1) * F + col];
        float o0 = q0, o1 = q1;
        if (tl == 0) o0 = present ? mean : q0;
        else         o1 = present ? mean : q1;
        out[((size_t)c * 2 + 0) * F + col] = o0;
        out[((size_t)c * 2 + 1) * F + col] = o1;
    }
}

extern "C" void kernel_launch(void* const* d_in, const int* in_sizes, int n_in,
                              void* d_out, int out_size, void* d_ws, size_t ws_size,
                              hipStream_t stream)
{
    const float* feat   = (const float*)d_in[0];
    const int*   labels = (const int*)d_in[1];
    const float* queue  = (const float*)d_in[2];
    const int*   tail   = (const int*)d_in[3];
    float* out = (float*)d_out;
    float* ws  = (float*)d_ws;

    const int N = in_sizes[1];   // number of rows

    // NB = number of accum blocks (power of two), sized to fit workspace.
    int NB = 256;
    while (NB > 32) {
        size_t need = ((size_t)NB * C * F + (size_t)NB * C + 64) * sizeof(float);
        if (need <= ws_size) break;
        NB >>= 1;
    }
    const int rpw = N / (NB * WPB);   // rows per wave

    float* psums = ws;
    float* pcnts = psums + (size_t)NB * C * F;

    hipLaunchKernelGGL(k_accum, dim3(NB),      dim3(256), 0, stream,
                       feat, labels, psums, pcnts, rpw);
    hipLaunchKernelGGL(k_tail,  dim3(C, 4),    dim3(256), 0, stream,
                       psums, pcnts, queue, tail, out, NB);
}